// Round 7
// baseline (151.713 us; speedup 1.0000x reference)
//
#include <hip/hip_runtime.h>

// Fused loss: 0.2 * mean(dx^2 - dy^2) + 0.8 * masked-MSE(target>0)
// dx = Sv(vert) ∘ D(horiz) on e = pred - target;  dy = D(vert) ∘ Sv(horiz)
//   Sv = [0.25, 1, 1.5, 1, 0.25], D = [-0.25, -0.5, 0, 0.5, 0.25]
// reflect-101 halo of 2 on e (exact; absmax 0.0 in R1-R6).
//
// R7 = R6 (async global_load_lds staging + plain-store partials; the R6
// atomic-elimination cut 93->46us) with the tile shrunk TH=32 -> 8:
// LDS 76 -> 25.4 KB lifts residency from 2 to 4 blocks/CU (VGPR-bound,
// 88<=128), doubling cross-block overlap of DMA-drain with compute.
// Vertical halo overfetch 1.125x -> 1.5x is L2-absorbed (adjacent-y blocks
// are 16 apart in dispatch order, ~1024 co-resident).

#define TW 256
#define TH 8
#define LROWS 12   // TH + 4
#define LW 264     // row stride (words): interior cols 4..259, halo 2,3,260,261

__device__ __forceinline__ int reflect101(int i, int n) {
    if (i < 0) i = -i;
    if (i >= n) i = 2 * n - 2 - i;
    return i;
}

__device__ __forceinline__ void async16(const float* g, float* l) {
    __builtin_amdgcn_global_load_lds(
        (const __attribute__((address_space(1))) void*)g,
        (__attribute__((address_space(3))) void*)l,
        16, 0, 0);
}

__global__ __launch_bounds__(256, 4) void loss_main(
    const float* __restrict__ pred, const float* __restrict__ target,
    float* __restrict__ part, int H, int W)
{
    __shared__ float psh[LROWS][LW];
    __shared__ float tsh[LROWS][LW];
    __shared__ float partials[4][3];

    const int tid  = threadIdx.x;
    const int lane = tid & 63;
    const int w    = tid >> 6;
    const int r0 = blockIdx.y * TH;
    const int c0 = blockIdx.x * TW;

    // ---- phase A: async global->LDS, 6 row-segments per wave, all in flight
    // idx 0..11 = pred rows, 12..23 = target rows. Wave-uniform rows.
#pragma unroll
    for (int j = 0; j < 6; ++j) {
        const int idx = j * 4 + w;
        const int row = (idx >= 12) ? idx - 12 : idx;
        const int gr  = reflect101(r0 - 2 + row, H);
        const size_t goff = (size_t)gr * W + c0 + lane * 4;
        if (idx >= 12) async16(target + goff, &tsh[row][4]);
        else           async16(pred   + goff, &psh[row][4]);
    }

    // ---- halo columns: 48 threads, 1 (row, halo-col) pair each, both tensors
    if (tid < 48) {
        const int row = tid >> 2;
        const int hc  = tid & 3;
        const int lc  = (hc < 2) ? (2 + hc) : (258 + hc);   // 2,3,260,261
        const int gc  = reflect101((hc < 2) ? (c0 - 2 + hc)
                                            : (c0 + 254 + hc), W);
        const int gr  = reflect101(r0 - 2 + row, H);
        const size_t off = (size_t)gr * W + gc;
        psh[row][lc] = pred[off];
        tsh[row][lc] = target[off];
    }
    __syncthreads();   // drains vmcnt(0): async DMA + halo ds_writes complete

    // ---- phase B: separable conv + masked MSE, rolling 5-row window ----
    // wave w: window LDS rows 2w..2w+5, owns output rows 2w+2, 2w+3
    const int cg = lane;            // output LDS cols 4+4cg .. 7+4cg
    const int rb = w * 2;
    float mse = 0.f, cnt = 0.f, g = 0.f;

    float4 D0, D1, D2, D3, D4, S0, S1, S2, S3, S4;

    auto hpass = [&](int rw, bool doMse, float4& D_, float4& S_) {
        const float4 p0 = *(const float4*)&psh[rw][4 * cg];
        const float4 p1 = *(const float4*)&psh[rw][4 * cg + 4];
        const float4 p2 = *(const float4*)&psh[rw][4 * cg + 8];
        const float4 t0 = *(const float4*)&tsh[rw][4 * cg];
        const float4 t1 = *(const float4*)&tsh[rw][4 * cg + 4];
        const float4 t2 = *(const float4*)&tsh[rw][4 * cg + 8];
        const float e0z = p0.z - t0.z, e0w = p0.w - t0.w;
        const float e1x = p1.x - t1.x, e1y = p1.y - t1.y;
        const float e1z = p1.z - t1.z, e1w = p1.w - t1.w;
        const float e2x = p2.x - t2.x, e2y = p2.y - t2.y;
        D_.x = 0.25f * (e1z - e0z) + 0.5f * (e1y - e0w);
        D_.y = 0.25f * (e1w - e0w) + 0.5f * (e1z - e1x);
        D_.z = 0.25f * (e2x - e1x) + 0.5f * (e1w - e1y);
        D_.w = 0.25f * (e2y - e1y) + 0.5f * (e2x - e1z);
        S_.x = 0.25f * (e0z + e1z) + (e0w + e1y) + 1.5f * e1x;
        S_.y = 0.25f * (e0w + e1w) + (e1x + e1z) + 1.5f * e1y;
        S_.z = 0.25f * (e1x + e2x) + (e1y + e1w) + 1.5f * e1z;
        S_.w = 0.25f * (e1y + e2y) + (e1z + e2x) + 1.5f * e1w;
        if (doMse) {
            if (t1.x > 0.f) { mse += e1x * e1x; cnt += 1.f; }
            if (t1.y > 0.f) { mse += e1y * e1y; cnt += 1.f; }
            if (t1.z > 0.f) { mse += e1z * e1z; cnt += 1.f; }
            if (t1.w > 0.f) { mse += e1w * e1w; cnt += 1.f; }
        }
    };

    hpass(rb + 0, false, D0, S0);
    hpass(rb + 1, false, D1, S1);
    hpass(rb + 2, true,  D2, S2);   // owned row: fuse MSE
    hpass(rb + 3, true,  D3, S3);   // owned row: fuse MSE

#pragma unroll
    for (int k = 0; k < 2; ++k) {
        hpass(rb + 4 + k, false, D4, S4);
        const float dx0 = 0.25f * (D0.x + D4.x) + (D1.x + D3.x) + 1.5f * D2.x;
        const float dx1 = 0.25f * (D0.y + D4.y) + (D1.y + D3.y) + 1.5f * D2.y;
        const float dx2 = 0.25f * (D0.z + D4.z) + (D1.z + D3.z) + 1.5f * D2.z;
        const float dx3 = 0.25f * (D0.w + D4.w) + (D1.w + D3.w) + 1.5f * D2.w;
        const float dy0 = 0.25f * (S4.x - S0.x) + 0.5f * (S3.x - S1.x);
        const float dy1 = 0.25f * (S4.y - S0.y) + 0.5f * (S3.y - S1.y);
        const float dy2 = 0.25f * (S4.z - S0.z) + 0.5f * (S3.z - S1.z);
        const float dy3 = 0.25f * (S4.w - S0.w) + 0.5f * (S3.w - S1.w);
        g += (dx0 * dx0 - dy0 * dy0) + (dx1 * dx1 - dy1 * dy1)
           + (dx2 * dx2 - dy2 * dy2) + (dx3 * dx3 - dy3 * dy3);
        D0 = D1; D1 = D2; D2 = D3; D3 = D4;
        S0 = S1; S1 = S2; S2 = S3; S3 = S4;
    }

    // ---- reduction: wave shuffle -> LDS partials -> PLAIN STORES (no atomics)
    for (int off = 32; off > 0; off >>= 1) {
        mse += __shfl_down(mse, off, 64);
        cnt += __shfl_down(cnt, off, 64);
        g   += __shfl_down(g,   off, 64);
    }
    if (lane == 0) {
        partials[w][0] = mse;
        partials[w][1] = cnt;
        partials[w][2] = g;
    }
    __syncthreads();
    if (tid == 0) {
        float m = 0.f, c2 = 0.f, gg = 0.f;
        for (int wv = 0; wv < 4; ++wv) {
            m  += partials[wv][0];
            c2 += partials[wv][1];
            gg += partials[wv][2];
        }
        const int bid = blockIdx.y * gridDim.x + blockIdx.x;
        float* slot = part + 3 * bid;
        slot[0] = m;
        slot[1] = c2;
        slot[2] = gg;
    }
}

__global__ __launch_bounds__(256) void loss_final(
    const float* __restrict__ part, int nslots,
    float* __restrict__ out, double inv_hw)
{
    __shared__ double red[4][3];
    double m = 0.0, c = 0.0, g = 0.0;
    for (int s = threadIdx.x; s < nslots; s += 256) {
        m += (double)part[3 * s];
        c += (double)part[3 * s + 1];
        g += (double)part[3 * s + 2];
    }
    for (int off = 32; off > 0; off >>= 1) {
        m += __shfl_down(m, off, 64);
        c += __shfl_down(c, off, 64);
        g += __shfl_down(g, off, 64);
    }
    const int w = threadIdx.x >> 6;
    if ((threadIdx.x & 63) == 0) { red[w][0] = m; red[w][1] = c; red[w][2] = g; }
    __syncthreads();
    if (threadIdx.x == 0) {
        m = red[0][0] + red[1][0] + red[2][0] + red[3][0];
        c = red[0][1] + red[1][1] + red[2][1] + red[3][1];
        g = red[0][2] + red[1][2] + red[2][2] + red[3][2];
        const double cnt = c < 1.0 ? 1.0 : c;
        out[0] = (float)(0.2 * (g * inv_hw) + 0.8 * (m / cnt));
    }
}

extern "C" void kernel_launch(void* const* d_in, const int* in_sizes, int n_in,
                              void* d_out, int out_size, void* d_ws, size_t ws_size,
                              hipStream_t stream) {
    const float* pred   = (const float*)d_in[0];
    const float* target = (const float*)d_in[1];
    float* out  = (float*)d_out;
    float* part = (float*)d_ws;

    const int H = 4096, W = 4096;
    const int nblocks = (W / TW) * (H / TH);   // 16 * 512 = 8192; 96 KB of ws

    dim3 grid(W / TW, H / TH);
    loss_main<<<grid, 256, 0, stream>>>(pred, target, part, H, W);
    loss_final<<<1, 256, 0, stream>>>(part, nblocks, out,
                                      1.0 / ((double)H * (double)W));
}

// Round 8
// 150.321 us; speedup vs baseline: 1.0093x; 1.0093x over previous
//
#include <hip/hip_runtime.h>

// Fused loss: 0.2 * mean(dx^2 - dy^2) + 0.8 * masked-MSE(target>0)
// dx = Sv(vert) ∘ D(horiz) on e = pred - target;  dy = D(vert) ∘ Sv(horiz)
//   Sv = [0.25, 1, 1.5, 1, 0.25], D = [-0.25, -0.5, 0, 0.5, 0.25]
// reflect-101 halo of 2 on e (exact; absmax 0.0 in R1-R7).
//
// R8 = R7 (async DMA staging, TH=8, plain-store partials) with the
// horizontal pass SHARED instead of redone per overlapping wave-window:
//   B1: each thread hpasses 3 of the 12 LDS rows -> registers (MSE fused)
//   barrier; write D,S in place over psh/tsh (interior cols only); barrier
//   B2: 5-tap vertical on shared D,S for 2 output rows per thread.
// Row-hpasses per block: 24 -> 12 (R7 waves re-hpassed neighbors' rows 3x).
// R7 evidence: L3-resident replay ran identical 44us -> issue-bound, not
// memory-bound; VALU is the pipe to cut (~-40% here).

#define TW 256
#define TH 8
#define LROWS 12   // TH + 4
#define LW 264     // row stride (words): interior cols 4..259, halo 2,3,260,261

__device__ __forceinline__ int reflect101(int i, int n) {
    if (i < 0) i = -i;
    if (i >= n) i = 2 * n - 2 - i;
    return i;
}

__device__ __forceinline__ void async16(const float* g, float* l) {
    __builtin_amdgcn_global_load_lds(
        (const __attribute__((address_space(1))) void*)g,
        (__attribute__((address_space(3))) void*)l,
        16, 0, 0);
}

__global__ __launch_bounds__(256) void loss_main(
    const float* __restrict__ pred, const float* __restrict__ target,
    float* __restrict__ part, int H, int W)
{
    __shared__ float psh[LROWS][LW];   // raw p, then horizontal-D after B1
    __shared__ float tsh[LROWS][LW];   // raw t, then horizontal-S after B1
    __shared__ float partials[4][3];

    const int tid  = threadIdx.x;
    const int lane = tid & 63;
    const int w    = tid >> 6;
    const int r0 = blockIdx.y * TH;
    const int c0 = blockIdx.x * TW;

    // ---- phase A: async global->LDS, 6 row-segments per wave, all in flight
    // idx 0..11 = pred rows, 12..23 = target rows. Wave-uniform rows.
#pragma unroll
    for (int j = 0; j < 6; ++j) {
        const int idx = j * 4 + w;
        const int row = (idx >= 12) ? idx - 12 : idx;
        const int gr  = reflect101(r0 - 2 + row, H);
        const size_t goff = (size_t)gr * W + c0 + lane * 4;
        if (idx >= 12) async16(target + goff, &tsh[row][4]);
        else           async16(pred   + goff, &psh[row][4]);
    }

    // ---- halo columns: 48 threads, 1 (row, halo-col) pair each, both tensors
    if (tid < 48) {
        const int row = tid >> 2;
        const int hc  = tid & 3;
        const int lc  = (hc < 2) ? (2 + hc) : (258 + hc);   // 2,3,260,261
        const int gc  = reflect101((hc < 2) ? (c0 - 2 + hc)
                                            : (c0 + 254 + hc), W);
        const int gr  = reflect101(r0 - 2 + row, H);
        const size_t off = (size_t)gr * W + gc;
        psh[row][lc] = pred[off];
        tsh[row][lc] = target[off];
    }
    __syncthreads();   // drains vmcnt(0): async DMA + halo ds_writes complete

    float mse = 0.f, cnt = 0.f, g = 0.f;

    // ---- B1: horizontal pass, each thread 3 rows (wave-uniform row per i)
    float4 Dh[3], Sh[3];
#pragma unroll
    for (int i = 0; i < 3; ++i) {
        const int row = i * 4 + w;                 // 0..11, each exactly once
        const float4 p0 = *(const float4*)&psh[row][4 * lane];
        const float4 p1 = *(const float4*)&psh[row][4 * lane + 4];
        const float4 p2 = *(const float4*)&psh[row][4 * lane + 8];
        const float4 t0 = *(const float4*)&tsh[row][4 * lane];
        const float4 t1 = *(const float4*)&tsh[row][4 * lane + 4];
        const float4 t2 = *(const float4*)&tsh[row][4 * lane + 8];
        const float e0z = p0.z - t0.z, e0w = p0.w - t0.w;
        const float e1x = p1.x - t1.x, e1y = p1.y - t1.y;
        const float e1z = p1.z - t1.z, e1w = p1.w - t1.w;
        const float e2x = p2.x - t2.x, e2y = p2.y - t2.y;
        Dh[i].x = 0.25f * (e1z - e0z) + 0.5f * (e1y - e0w);
        Dh[i].y = 0.25f * (e1w - e0w) + 0.5f * (e1z - e1x);
        Dh[i].z = 0.25f * (e2x - e1x) + 0.5f * (e1w - e1y);
        Dh[i].w = 0.25f * (e2y - e1y) + 0.5f * (e2x - e1z);
        Sh[i].x = 0.25f * (e0z + e1z) + (e0w + e1y) + 1.5f * e1x;
        Sh[i].y = 0.25f * (e0w + e1w) + (e1x + e1z) + 1.5f * e1y;
        Sh[i].z = 0.25f * (e1x + e2x) + (e1y + e1w) + 1.5f * e1z;
        Sh[i].w = 0.25f * (e1y + e2y) + (e1z + e2x) + 1.5f * e1w;
        if (row >= 2 && row < 10) {    // owned image rows: fuse masked MSE
            if (t1.x > 0.f) { mse += e1x * e1x; cnt += 1.f; }
            if (t1.y > 0.f) { mse += e1y * e1y; cnt += 1.f; }
            if (t1.z > 0.f) { mse += e1z * e1z; cnt += 1.f; }
            if (t1.w > 0.f) { mse += e1w * e1w; cnt += 1.f; }
        }
    }
    __syncthreads();   // all raw reads done -> safe to overwrite in place

#pragma unroll
    for (int i = 0; i < 3; ++i) {
        const int row = i * 4 + w;
        *(float4*)&psh[row][4 + 4 * lane] = Dh[i];   // interior cols only
        *(float4*)&tsh[row][4 + 4 * lane] = Sh[i];
    }
    __syncthreads();

    // ---- B2: 5-tap vertical on shared D,S; 2 output rows per thread
#pragma unroll
    for (int i = 0; i < 2; ++i) {
        const int ro = 2 + i * 4 + w;               // LDS rows 2..9
        const float4 d0 = *(const float4*)&psh[ro - 2][4 + 4 * lane];
        const float4 d1 = *(const float4*)&psh[ro - 1][4 + 4 * lane];
        const float4 d2 = *(const float4*)&psh[ro    ][4 + 4 * lane];
        const float4 d3 = *(const float4*)&psh[ro + 1][4 + 4 * lane];
        const float4 d4 = *(const float4*)&psh[ro + 2][4 + 4 * lane];
        const float4 s0 = *(const float4*)&tsh[ro - 2][4 + 4 * lane];
        const float4 s1 = *(const float4*)&tsh[ro - 1][4 + 4 * lane];
        const float4 s2 = *(const float4*)&tsh[ro    ][4 + 4 * lane];
        const float4 s3 = *(const float4*)&tsh[ro + 1][4 + 4 * lane];
        const float4 s4 = *(const float4*)&tsh[ro + 2][4 + 4 * lane];
        const float dx0 = 0.25f * (d0.x + d4.x) + (d1.x + d3.x) + 1.5f * d2.x;
        const float dx1 = 0.25f * (d0.y + d4.y) + (d1.y + d3.y) + 1.5f * d2.y;
        const float dx2 = 0.25f * (d0.z + d4.z) + (d1.z + d3.z) + 1.5f * d2.z;
        const float dx3 = 0.25f * (d0.w + d4.w) + (d1.w + d3.w) + 1.5f * d2.w;
        const float dy0 = 0.25f * (s4.x - s0.x) + 0.5f * (s3.x - s1.x);
        const float dy1 = 0.25f * (s4.y - s0.y) + 0.5f * (s3.y - s1.y);
        const float dy2 = 0.25f * (s4.z - s0.z) + 0.5f * (s3.z - s1.z);
        const float dy3 = 0.25f * (s4.w - s0.w) + 0.5f * (s3.w - s1.w);
        g += (dx0 * dx0 - dy0 * dy0) + (dx1 * dx1 - dy1 * dy1)
           + (dx2 * dx2 - dy2 * dy2) + (dx3 * dx3 - dy3 * dy3);
    }

    // ---- reduction: wave shuffle -> LDS partials -> PLAIN STORES (no atomics)
    for (int off = 32; off > 0; off >>= 1) {
        mse += __shfl_down(mse, off, 64);
        cnt += __shfl_down(cnt, off, 64);
        g   += __shfl_down(g,   off, 64);
    }
    if (lane == 0) {
        partials[w][0] = mse;
        partials[w][1] = cnt;
        partials[w][2] = g;
    }
    __syncthreads();
    if (tid == 0) {
        float m = 0.f, c2 = 0.f, gg = 0.f;
        for (int wv = 0; wv < 4; ++wv) {
            m  += partials[wv][0];
            c2 += partials[wv][1];
            gg += partials[wv][2];
        }
        const int bid = blockIdx.y * gridDim.x + blockIdx.x;
        float* slot = part + 3 * bid;
        slot[0] = m;
        slot[1] = c2;
        slot[2] = gg;
    }
}

__global__ __launch_bounds__(256) void loss_final(
    const float* __restrict__ part, int nslots,
    float* __restrict__ out, double inv_hw)
{
    __shared__ double red[4][3];
    double m = 0.0, c = 0.0, g = 0.0;
    for (int s = threadIdx.x; s < nslots; s += 256) {
        m += (double)part[3 * s];
        c += (double)part[3 * s + 1];
        g += (double)part[3 * s + 2];
    }
    for (int off = 32; off > 0; off >>= 1) {
        m += __shfl_down(m, off, 64);
        c += __shfl_down(c, off, 64);
        g += __shfl_down(g, off, 64);
    }
    const int w = threadIdx.x >> 6;
    if ((threadIdx.x & 63) == 0) { red[w][0] = m; red[w][1] = c; red[w][2] = g; }
    __syncthreads();
    if (threadIdx.x == 0) {
        m = red[0][0] + red[1][0] + red[2][0] + red[3][0];
        c = red[0][1] + red[1][1] + red[2][1] + red[3][1];
        g = red[0][2] + red[1][2] + red[2][2] + red[3][2];
        const double cnt = c < 1.0 ? 1.0 : c;
        out[0] = (float)(0.2 * (g * inv_hw) + 0.8 * (m / cnt));
    }
}

extern "C" void kernel_launch(void* const* d_in, const int* in_sizes, int n_in,
                              void* d_out, int out_size, void* d_ws, size_t ws_size,
                              hipStream_t stream) {
    const float* pred   = (const float*)d_in[0];
    const float* target = (const float*)d_in[1];
    float* out  = (float*)d_out;
    float* part = (float*)d_ws;

    const int H = 4096, W = 4096;
    const int nblocks = (W / TW) * (H / TH);   // 16 * 512 = 8192; 96 KB of ws

    dim3 grid(W / TW, H / TH);
    loss_main<<<grid, 256, 0, stream>>>(pred, target, part, H, W);
    loss_final<<<1, 256, 0, stream>>>(part, nblocks, out,
                                      1.0 / ((double)H * (double)W));
}